// Round 11
// baseline (2509.181 us; speedup 1.0000x reference)
//
#include <hip/hip_runtime.h>
#include <hip/hip_fp16.h>
#include <stdint.h>

#define T_LEN 2048
#define L     1024
#define NFB   64            // forward blocks: 0..63; backward: 64..127
#define GOLDB 128           // gold block
#define CPB   16            // columns (rows) per block; 4 per wave
#define TPB   256
#define TMID  1023          // forward computes f_{1023}
#define BSTEPS 1024         // backward steps s=1..1024 (emission row t=2048-s)
#define SPIN_MAX (1 << 14)

#define SCOPE_AGENT __HIP_MEMORY_SCOPE_AGENT
#define LDA(p) __hip_atomic_load((p), __ATOMIC_RELAXED, SCOPE_AGENT)
#define STA(p, v) __hip_atomic_store((p), (v), __ATOMIC_RELAXED, SCOPE_AGENT)

// ws64 layout (packed kernel): fpk0[512] fpk1[512] bpk0[512] bpk1[512]
//   aF[2][8] aB[2][8] gold  => 2081 u64 = 16648 B required.
#define OFF_FPK0 0
#define OFF_FPK1 512
#define OFF_BPK0 1024
#define OFF_BPK1 1536
#define OFF_AF   2048
#define OFF_AB   2064
#define OFF_GOLD 2080
#define WS_NEED  (2081 * 8)

__device__ __forceinline__ uint64_t pack_su(int tag, float v) {
    return ((uint64_t)(uint32_t)tag << 32) | (uint64_t)__float_as_uint(v);
}
__device__ __forceinline__ float h2f_lo(uint32_t w) {
    return __half2float(__ushort_as_half((unsigned short)(w & 0xffffu)));
}
__device__ __forceinline__ float h2f_hi(uint32_t w) {
    return __half2float(__ushort_as_half((unsigned short)(w >> 16)));
}

// =====================================================================
// Packed meet-in-the-middle kernel.
// =====================================================================
__global__ __launch_bounds__(TPB, 1)
void crf_mitm_pk(const float* __restrict__ feats,
                 const float* __restrict__ transfer,
                 const int* __restrict__ target,
                 float* __restrict__ out,
                 uint64_t* __restrict__ ws64)
{
    __shared__ __align__(16) float qbuf[2][L];      // 8 KB, double-buffered
    __shared__ float red[8];

    uint64_t* fpk0 = ws64 + OFF_FPK0;
    uint64_t* fpk1 = ws64 + OFF_FPK1;
    uint64_t* bpk0 = ws64 + OFF_BPK0;
    uint64_t* bpk1 = ws64 + OFF_BPK1;
    uint64_t* aF   = ws64 + OFF_AF;                 // [parity*8 + copy]
    uint64_t* aB   = ws64 + OFF_AB;
    uint64_t* goldslot = ws64 + OFF_GOLD;

    const int b    = blockIdx.x;
    const int tid  = threadIdx.x;
    const int lane = tid & 63;
    const int wv   = tid >> 6;                      // wave 0..3
    const int cl   = 2 * (lane & 1) + ((lane >> 1) & 1);   // bijective on lanes 0..3

    // ---------------- gold-score block ----------------
    if (b == GOLDB) {
        float s = 0.f;
        for (int t = tid; t < T_LEN; t += TPB)
            s += feats[t * L + target[t]];
        for (int t = tid; t < T_LEN - 1; t += TPB)
            s += transfer[target[t] * L + target[t + 1]];
        #pragma unroll
        for (int m = 32; m; m >>= 1) s += __shfl_xor(s, m, 64);
        if (lane == 0) red[wv] = s;
        __syncthreads();
        if (tid == 0) {
            float g = red[0] + red[1] + red[2] + red[3];
            STA(goldslot, pack_su(1, g));
        }
        return;
    }

    if (b < NFB) {
        // ================= FORWARD chain (1023 steps) =================
        const int gcb   = b * CPB + 4 * wv;         // wave's first global column
        const int pbase = 8 * b + 2 * wv;           // wave's first pair slot
        const int acopy = b & 7;

        float E[16][4];                             // E[k][c]=exp(transfer[lane+64k][gcb+c])
        #pragma unroll
        for (int k = 0; k < 16; ++k) {
            const float4 r = *(const float4*)(transfer + (size_t)(lane + 64 * k) * L + gcb);
            E[k][0] = __expf(r.x); E[k][1] = __expf(r.y);
            E[k][2] = __expf(r.z); E[k][3] = __expf(r.w);
        }

        // init tag 0: deltas relative to 0 -> raw feats[0][*] as fp16
        if (tid < 8) {
            const int p = 8 * b + tid;              // pair p: cols 2p, 2p+1
            unsigned short h0 = __half_as_ushort(__float2half_rn(feats[2 * p]));
            unsigned short h1 = __half_as_ushort(__float2half_rn(feats[2 * p + 1]));
            STA(&fpk0[p], (uint64_t)(((uint32_t)h1 << 16) | h0));   // tag 0
        }
        if (b == 0 && tid == 0) {
            uint64_t av = pack_su(0, feats[0]);
            #pragma unroll
            for (int c = 0; c < 8; ++c) STA(&aF[c], av);            // parity 0
        }

        float aprev = 0.f;                          // anchor(t-2); anchor(-1) = 0
        float alast = 0.f;                          // anchor(1022) after the loop

        for (int t = 1; t <= TMID; ++t) {
            const uint64_t* rpk = (t & 1) ? fpk0 : fpk1;    // tag t-1
            uint64_t*       wpk = (t & 1) ? fpk1 : fpk0;    // tag t
            const uint64_t* ranch = aF + ((t & 1) ? 0 : 8) + acopy;
            uint64_t*       wanch = aF + ((t & 1) ? 8 : 0);
            const int expect = t - 1;

            const float fe = feats[(size_t)t * L + gcb + cl];   // overlaps poll

            uint64_t p0, p1, va;
            int n = 0;
            for (;;) {
                p0 = LDA(rpk + 2 * tid);
                p1 = LDA(rpk + 2 * tid + 1);
                va = LDA(ranch);
                bool ready = ((int)(p0 >> 32) == expect) & ((int)(p1 >> 32) == expect) &
                             ((int)(va >> 32) == expect);
                if (ready || ++n >= SPIN_MAX) break;
            }
            const float anow = __uint_as_float((uint32_t)va);
            const float dsh  = anow - aprev;

            const uint32_t l0 = (uint32_t)p0, l1 = (uint32_t)p1;
            float* qb = qbuf[t & 1];
            float4 qv;
            qv.x = __expf(h2f_lo(l0) - dsh);
            qv.y = __expf(h2f_hi(l0) - dsh);
            qv.z = __expf(h2f_lo(l1) - dsh);
            qv.w = __expf(h2f_hi(l1) - dsh);
            ((float4*)qb)[tid] = qv;
            __syncthreads();

            float a0 = 0.f, a1 = 0.f, a2 = 0.f, a3 = 0.f;
            #pragma unroll
            for (int k = 0; k < 16; ++k) {
                const float q = qb[lane + 64 * k];   // conflict-free ds_read_b32
                a0 += q * E[k][0]; a1 += q * E[k][1];
                a2 += q * E[k][2]; a3 += q * E[k][3];
            }

            {   // split-reduction: 4 accs -> 1 per lane (col = cl)
                const bool h1b = lane & 1;
                float s0 = h1b ? a0 : a2;  float r0 = __shfl_xor(s0, 1, 64);
                float s1 = h1b ? a1 : a3;  float r1 = __shfl_xor(s1, 1, 64);
                a0 = (h1b ? a2 : a0) + r0;
                a1 = (h1b ? a3 : a1) + r1;
                const bool h2b = lane & 2;
                float s2 = h2b ? a0 : a1;  float r2 = __shfl_xor(s2, 2, 64);
                a0 = (h2b ? a1 : a0) + r2;
            }
            float s = a0;
            s += __shfl_xor(s, 4, 64);
            s += __shfl_xor(s, 8, 64);
            s += __shfl_xor(s, 16, 64);
            s += __shfl_xor(s, 32, 64);

            const float nv = anow + __logf(s) + fe;  // new score for col gcb+cl
            // pack 2 fp16 deltas + tag, publish (lanes 0,1 per wave)
            unsigned short hb = __half_as_ushort(__float2half_rn(nv - anow));
            int ho = __shfl_xor((int)hb, 2, 64);     // lane0<-lane2 (c1), lane1<-lane3 (c3)
            uint64_t pv = ((uint64_t)(uint32_t)t << 32) |
                          (uint32_t)(((uint32_t)(ho & 0xffff) << 16) | hb);
            if (b == 0 && tid == 0) {                // col 0 anchor, replicated x8
                uint64_t av = pack_su(t, nv);
                #pragma unroll
                for (int c = 0; c < 8; ++c) STA(wanch + c, av);
            }
            if (lane < 2) STA(&wpk[pbase + lane], pv);

            aprev = anow;
            alast = anow;
        }

        // ---------- block 0: combine logZ = lse(f_{1023}+b_{1023}) - gold ----------
        if (b == 0) {
            const uint64_t* ab = aB + 8;            // parity 1, copy 0: tag 1023
            uint64_t f0, f1, g0, g1, va;
            int n = 0;
            for (;;) {
                f0 = LDA(fpk1 + 2 * tid); f1 = LDA(fpk1 + 2 * tid + 1);   // tag 1023
                g0 = LDA(bpk0 + 2 * tid); g1 = LDA(bpk0 + 2 * tid + 1);   // tag 1024
                va = LDA(ab);
                bool ready = ((int)(f0 >> 32) == TMID) & ((int)(f1 >> 32) == TMID) &
                             ((int)(g0 >> 32) == BSTEPS) & ((int)(g1 >> 32) == BSTEPS) &
                             ((int)(va >> 32) == TMID);
                if (ready || ++n >= SPIN_MAX) break;
            }
            const float anchB = __uint_as_float((uint32_t)va);
            const uint32_t lf0 = (uint32_t)f0, lf1 = (uint32_t)f1;
            const uint32_t lg0 = (uint32_t)g0, lg1 = (uint32_t)g1;
            float sv[4] = { h2f_lo(lf0) + h2f_lo(lg0), h2f_hi(lf0) + h2f_hi(lg0),
                            h2f_lo(lf1) + h2f_lo(lg1), h2f_hi(lf1) + h2f_hi(lg1) };
            float mx = fmaxf(fmaxf(sv[0], sv[1]), fmaxf(sv[2], sv[3]));
            #pragma unroll
            for (int m = 32; m; m >>= 1) mx = fmaxf(mx, __shfl_xor(mx, m, 64));
            if (lane == 0) red[wv] = mx;
            __syncthreads();
            const float M = fmaxf(fmaxf(red[0], red[1]), fmaxf(red[2], red[3]));
            float sm = 0.f;
            #pragma unroll
            for (int k = 0; k < 4; ++k) sm += __expf(sv[k] - M);
            #pragma unroll
            for (int m = 32; m; m >>= 1) sm += __shfl_xor(sm, m, 64);
            if (lane == 0) red[4 + wv] = sm;
            __syncthreads();
            if (tid == 0) {
                const float S = red[4] + red[5] + red[6] + red[7];
                const float lse = alast + anchB + M + __logf(S);
                uint64_t g = LDA(goldslot);
                int n2 = 0;
                while ((int)(g >> 32) < 1 && ++n2 < SPIN_MAX) g = LDA(goldslot);
                out[0] = lse - __uint_as_float((uint32_t)g);
            }
        }
        return;
    }

    // ================= BACKWARD chain (blocks 64..127, 1024 steps) =================
    {
        const int rb      = b - NFB;                // 0..63
        const int rowbase = rb * CPB + 4 * wv;      // wave's first global row
        const int pbase   = 8 * rb + 2 * wv;
        const int acopy   = rb & 7;

        // E[k][r] = exp(transfer[(rowbase+r)*L + lane+64k]) — coalesced staging
        float E[16][4];
        #pragma unroll
        for (int r = 0; r < 4; ++r) {
            const float* rowp = transfer + (size_t)(rowbase + r) * L + lane;
            #pragma unroll
            for (int k = 0; k < 16; ++k)
                E[k][r] = __expf(rowp[64 * k]);
        }

        // init tag 0: b = 0 everywhere -> packed word is exactly 0
        if (tid < 8) STA(&bpk0[8 * rb + tid], (uint64_t)0);
        if (rb == 0 && tid == 0) {
            uint64_t av = pack_su(0, 0.f);
            #pragma unroll
            for (int c = 0; c < 8; ++c) STA(&aB[c], av);            // parity 0
        }

        float aprev = 0.f;

        for (int s = 1; s <= BSTEPS; ++s) {
            const uint64_t* rpk = (s & 1) ? bpk0 : bpk1;    // tag s-1
            uint64_t*       wpk = (s & 1) ? bpk1 : bpk0;    // tag s
            const uint64_t* ranch = aB + ((s & 1) ? 0 : 8) + acopy;
            uint64_t*       wanch = aB + ((s & 1) ? 8 : 0);
            const int expect = s - 1;
            const int t = T_LEN - s;                // emission row

            const float4 fv = *(const float4*)(feats + (size_t)t * L + 4 * tid);

            uint64_t p0, p1, va;
            int n = 0;
            for (;;) {
                p0 = LDA(rpk + 2 * tid);
                p1 = LDA(rpk + 2 * tid + 1);
                va = LDA(ranch);
                bool ready = ((int)(p0 >> 32) == expect) & ((int)(p1 >> 32) == expect) &
                             ((int)(va >> 32) == expect);
                if (ready || ++n >= SPIN_MAX) break;
            }
            const float anow = __uint_as_float((uint32_t)va);
            const float dsh  = anow - aprev;

            const uint32_t l0 = (uint32_t)p0, l1 = (uint32_t)p1;
            float* qb = qbuf[s & 1];
            float4 wv4;
            wv4.x = __expf(fv.x + h2f_lo(l0) - dsh);
            wv4.y = __expf(fv.y + h2f_hi(l0) - dsh);
            wv4.z = __expf(fv.z + h2f_lo(l1) - dsh);
            wv4.w = __expf(fv.w + h2f_hi(l1) - dsh);
            ((float4*)qb)[tid] = wv4;
            __syncthreads();

            float a0 = 0.f, a1 = 0.f, a2 = 0.f, a3 = 0.f;
            #pragma unroll
            for (int k = 0; k < 16; ++k) {
                const float w = qb[lane + 64 * k];
                a0 += w * E[k][0]; a1 += w * E[k][1];
                a2 += w * E[k][2]; a3 += w * E[k][3];
            }

            {   // split-reduction: 4 accs -> 1 per lane (row = cl)
                const bool h1b = lane & 1;
                float s0 = h1b ? a0 : a2;  float r0 = __shfl_xor(s0, 1, 64);
                float s1 = h1b ? a1 : a3;  float r1 = __shfl_xor(s1, 1, 64);
                a0 = (h1b ? a2 : a0) + r0;
                a1 = (h1b ? a3 : a1) + r1;
                const bool h2b = lane & 2;
                float s2 = h2b ? a0 : a1;  float r2 = __shfl_xor(s2, 2, 64);
                a0 = (h2b ? a1 : a0) + r2;
            }
            float sum = a0;
            sum += __shfl_xor(sum, 4, 64);
            sum += __shfl_xor(sum, 8, 64);
            sum += __shfl_xor(sum, 16, 64);
            sum += __shfl_xor(sum, 32, 64);

            const float nb = anow + __logf(sum);    // emission already inside w
            unsigned short hb = __half_as_ushort(__float2half_rn(nb - anow));
            int ho = __shfl_xor((int)hb, 2, 64);
            uint64_t pv = ((uint64_t)(uint32_t)s << 32) |
                          (uint32_t)(((uint32_t)(ho & 0xffff) << 16) | hb);
            if (rb == 0 && tid == 0) {              // row 0 anchor, replicated x8
                uint64_t av = pack_su(s, nb);
                #pragma unroll
                for (int c = 0; c < 8; ++c) STA(wanch + c, av);
            }
            if (lane < 2) STA(&wpk[pbase + lane], pv);

            aprev = anow;
        }
    }
}

// =====================================================================
// Fallback: proven R4 single-forward-chain kernel (needs 16392 B ws).
// =====================================================================
__global__ __launch_bounds__(TPB, 1)
void crf_single(const float* __restrict__ feats,
                const float* __restrict__ transfer,
                const int* __restrict__ target,
                float* __restrict__ out,
                uint64_t* __restrict__ ws64)
{
    __shared__ __align__(16) float qbuf[2][L];
    __shared__ float red[8];

    uint64_t* buf0 = ws64;
    uint64_t* buf1 = ws64 + L;
    uint64_t* goldslot = ws64 + 2 * L;

    const int b   = blockIdx.x;
    const int tid = threadIdx.x;
    const int lane = tid & 63;
    const int wv   = tid >> 6;
    const int cl   = 2 * (lane & 1) + ((lane >> 1) & 1);

    if (b == NFB) {
        float s = 0.f;
        for (int t = tid; t < T_LEN; t += TPB)
            s += feats[t * L + target[t]];
        for (int t = tid; t < T_LEN - 1; t += TPB)
            s += transfer[target[t] * L + target[t + 1]];
        #pragma unroll
        for (int m = 32; m; m >>= 1) s += __shfl_xor(s, m, 64);
        if (lane == 0) red[wv] = s;
        __syncthreads();
        if (tid == 0) {
            float g = red[0] + red[1] + red[2] + red[3];
            STA(goldslot, pack_su(1, g));
        }
        return;
    }

    const int gcb    = b * CPB + 4 * wv;
    const int shslot = b * CPB;

    float E[16][4];
    #pragma unroll
    for (int k = 0; k < 16; ++k) {
        const float4 r = *(const float4*)(transfer + (size_t)(lane + 64 * k) * L + gcb);
        E[k][0] = __expf(r.x); E[k][1] = __expf(r.y);
        E[k][2] = __expf(r.z); E[k][3] = __expf(r.w);
    }

    if (tid < CPB) {
        int j = b * CPB + tid;
        STA(&buf0[j], pack_su(0, feats[j]));
    }

    for (int t = 1; t < T_LEN; ++t) {
        uint64_t* rbuf = (t & 1) ? buf0 : buf1;
        uint64_t* wbuf = (t & 1) ? buf1 : buf0;
        const int expect = t - 1;
        const float fe = feats[(size_t)t * L + gcb + cl];

        const uint64_t* rp = rbuf + 4 * tid;
        uint64_t v0, v1, v2, v3, vs;
        int n = 0;
        for (;;) {
            v0 = LDA(rp + 0); v1 = LDA(rp + 1);
            v2 = LDA(rp + 2); v3 = LDA(rp + 3);
            vs = LDA(rbuf + shslot);
            bool ready = ((int)(v0 >> 32) >= expect) & ((int)(v1 >> 32) >= expect) &
                         ((int)(v2 >> 32) >= expect) & ((int)(v3 >> 32) >= expect) &
                         ((int)(vs >> 32) >= expect);
            if (ready || ++n >= SPIN_MAX) break;
        }
        const float sloc = __uint_as_float((uint32_t)vs);

        float* qb = qbuf[t & 1];
        float4 qv;
        qv.x = __expf(__uint_as_float((uint32_t)v0) - sloc);
        qv.y = __expf(__uint_as_float((uint32_t)v1) - sloc);
        qv.z = __expf(__uint_as_float((uint32_t)v2) - sloc);
        qv.w = __expf(__uint_as_float((uint32_t)v3) - sloc);
        ((float4*)qb)[tid] = qv;
        __syncthreads();

        float a0 = 0.f, a1 = 0.f, a2 = 0.f, a3 = 0.f;
        #pragma unroll
        for (int k = 0; k < 16; ++k) {
            const float q = qb[lane + 64 * k];
            a0 += q * E[k][0]; a1 += q * E[k][1];
            a2 += q * E[k][2]; a3 += q * E[k][3];
        }
        {
            const bool h1 = lane & 1;
            float s0 = h1 ? a0 : a2;  float r0 = __shfl_xor(s0, 1, 64);
            float s1 = h1 ? a1 : a3;  float r1 = __shfl_xor(s1, 1, 64);
            a0 = (h1 ? a2 : a0) + r0;
            a1 = (h1 ? a3 : a1) + r1;
            const bool h2 = lane & 2;
            float s2 = h2 ? a0 : a1;  float r2 = __shfl_xor(s2, 2, 64);
            a0 = (h2 ? a1 : a0) + r2;
        }
        float s = a0;
        s += __shfl_xor(s, 4, 64);
        s += __shfl_xor(s, 8, 64);
        s += __shfl_xor(s, 16, 64);
        s += __shfl_xor(s, 32, 64);

        const float nv = sloc + __logf(s) + fe;
        if (lane < 4)
            STA(&wbuf[gcb + cl], pack_su(t, nv));
    }

    if (b == 0) {
        const uint64_t* fp = buf1 + 4 * tid;
        uint64_t v0, v1, v2, v3;
        int n = 0;
        for (;;) {
            v0 = LDA(fp + 0); v1 = LDA(fp + 1);
            v2 = LDA(fp + 2); v3 = LDA(fp + 3);
            bool ready = ((int)(v0 >> 32) >= T_LEN - 1) & ((int)(v1 >> 32) >= T_LEN - 1) &
                         ((int)(v2 >> 32) >= T_LEN - 1) & ((int)(v3 >> 32) >= T_LEN - 1);
            if (ready || ++n >= SPIN_MAX) break;
        }
        float sv[4] = { __uint_as_float((uint32_t)v0), __uint_as_float((uint32_t)v1),
                        __uint_as_float((uint32_t)v2), __uint_as_float((uint32_t)v3) };
        float mx = fmaxf(fmaxf(sv[0], sv[1]), fmaxf(sv[2], sv[3]));
        #pragma unroll
        for (int m = 32; m; m >>= 1) mx = fmaxf(mx, __shfl_xor(mx, m, 64));
        if (lane == 0) red[wv] = mx;
        __syncthreads();
        const float M = fmaxf(fmaxf(red[0], red[1]), fmaxf(red[2], red[3]));
        float sm = 0.f;
        #pragma unroll
        for (int k = 0; k < 4; ++k) sm += __expf(sv[k] - M);
        #pragma unroll
        for (int m = 32; m; m >>= 1) sm += __shfl_xor(sm, m, 64);
        if (lane == 0) red[4 + wv] = sm;
        __syncthreads();
        if (tid == 0) {
            const float S = red[4] + red[5] + red[6] + red[7];
            const float lse = M + __logf(S);
            uint64_t g = LDA(goldslot);
            int n2 = 0;
            while ((int)(g >> 32) < 1 && ++n2 < SPIN_MAX) g = LDA(goldslot);
            out[0] = lse - __uint_as_float((uint32_t)g);
        }
    }
}

extern "C" void kernel_launch(void* const* d_in, const int* in_sizes, int n_in,
                              void* d_out, int out_size, void* d_ws, size_t ws_size,
                              hipStream_t stream) {
    const float* feats    = (const float*)d_in[0];
    const float* transfer = (const float*)d_in[1];
    const int*   target   = (const int*)d_in[2];
    float* out = (float*)d_out;
    uint64_t* ws64 = (uint64_t*)d_ws;

    if (ws_size >= WS_NEED) {
        hipLaunchKernelGGL(crf_mitm_pk, dim3(GOLDB + 1), dim3(TPB), 0, stream,
                           feats, transfer, target, out, ws64);
    } else {
        hipLaunchKernelGGL(crf_single, dim3(NFB + 1), dim3(TPB), 0, stream,
                           feats, transfer, target, out, ws64);
    }
}

// Round 13
// 2298.604 us; speedup vs baseline: 1.0916x; 1.0916x over previous
//
#include <hip/hip_runtime.h>
#include <stdint.h>

#define T_LEN 2048
#define L     1024
#define NFB   64            // forward blocks: 0..63
#define GOLDB 128           // gold block (meet-in-middle grid)
#define CPB   16            // columns (rows) per block; 4 per wave
#define TPB   256
#define TMID  1023          // forward computes f_{1023}; backward computes b_{1023}
#define BSTEPS 1024         // backward step count (s=1..1024, emission row t=2048-s)
#define SPIN_MAX (1 << 14)  // bounded: wedge exits in ~2s, normal use ~1-3 iters

#define SCOPE_AGENT __HIP_MEMORY_SCOPE_AGENT
#define LDA(p) __hip_atomic_load((p), __ATOMIC_RELAXED, SCOPE_AGENT)
#define STA(p, v) __hip_atomic_store((p), (v), __ATOMIC_RELAXED, SCOPE_AGENT)

__device__ __forceinline__ uint64_t pack_su(int tag, float v) {
    return ((uint64_t)(uint32_t)tag << 32) | (uint64_t)__float_as_uint(v);
}

// =====================================================================
// Meet-in-the-middle kernel: forward chain (blocks 0..63, 1023 steps) +
// backward chain (blocks 64..127, 1024 steps) + gold block (128).
// Requires ws >= (4*L + 1) * 8 = 32776 bytes.
// Champion structure (R10, 2.30 ms verified): block-local shift slot,
// tag-fused u64 publish, register-resident E, one barrier per step.
// Do NOT replace the block-local shift with a cross-block anchor (R11:
// +9%, outliers). Do NOT widen per-wave poll coverage (R3: livelock).
// =====================================================================
__global__ __launch_bounds__(TPB, 1)
void crf_mitm(const float* __restrict__ feats,
              const float* __restrict__ transfer,
              const int* __restrict__ target,
              float* __restrict__ out,
              uint64_t* __restrict__ ws64)
{
    __shared__ __align__(16) float qbuf[2][L];      // 8 KB, double-buffered
    __shared__ float red[8];

    uint64_t* fb0 = ws64;                           // forward tagged buffers
    uint64_t* fb1 = ws64 + L;
    uint64_t* bb0 = ws64 + 2 * L;                   // backward tagged buffers
    uint64_t* bb1 = ws64 + 3 * L;
    uint64_t* goldslot = ws64 + 4 * L;

    const int b    = blockIdx.x;
    const int tid  = threadIdx.x;
    const int lane = tid & 63;
    const int wv   = tid >> 6;                      // wave 0..3
    // lane -> slot-within-wave mapping fixed by the split-reduction below:
    const int cl   = 2 * (lane & 1) + ((lane >> 1) & 1);   // bijective on lanes 0..3

    // ---------------- gold-score block ----------------
    if (b == GOLDB) {
        float s = 0.f;
        for (int t = tid; t < T_LEN; t += TPB)
            s += feats[t * L + target[t]];
        for (int t = tid; t < T_LEN - 1; t += TPB)
            s += transfer[target[t] * L + target[t + 1]];
        #pragma unroll
        for (int m = 32; m; m >>= 1) s += __shfl_xor(s, m, 64);
        if (lane == 0) red[wv] = s;
        __syncthreads();
        if (tid == 0) {
            float g = red[0] + red[1] + red[2] + red[3];
            STA(goldslot, pack_su(1, g));
        }
        return;
    }

    if (b < NFB) {
        // ================= FORWARD chain (1023 steps) =================
        const int gcb    = b * CPB + 4 * wv;        // wave's first global column
        const int shslot = b * CPB;                 // block-LOCAL exp-shift slot

        float E[16][4];                             // E[k][c]=exp(transfer[lane+64k][gcb+c])
        #pragma unroll
        for (int k = 0; k < 16; ++k) {
            const float4 r = *(const float4*)(transfer + (size_t)(lane + 64 * k) * L + gcb);
            E[k][0] = __expf(r.x); E[k][1] = __expf(r.y);
            E[k][2] = __expf(r.z); E[k][3] = __expf(r.w);
        }

        if (tid < CPB) {
            int j = b * CPB + tid;
            STA(&fb0[j], pack_su(0, feats[j]));
        }

        for (int t = 1; t <= TMID; ++t) {
            uint64_t* rbuf = (t & 1) ? fb0 : fb1;
            uint64_t* wbuf = (t & 1) ? fb1 : fb0;
            const int expect = t - 1;

            const float fe = feats[(size_t)t * L + gcb + cl];   // overlaps poll

            const uint64_t* rp = rbuf + 4 * tid;
            uint64_t v0, v1, v2, v3, vs;
            int n = 0;
            for (;;) {
                v0 = LDA(rp + 0); v1 = LDA(rp + 1);
                v2 = LDA(rp + 2); v3 = LDA(rp + 3);
                vs = LDA(rbuf + shslot);
                bool ready = ((int)(v0 >> 32) >= expect) & ((int)(v1 >> 32) >= expect) &
                             ((int)(v2 >> 32) >= expect) & ((int)(v3 >> 32) >= expect) &
                             ((int)(vs >> 32) >= expect);
                if (ready || ++n >= SPIN_MAX) break;
            }
            const float sloc = __uint_as_float((uint32_t)vs);

            float* qb = qbuf[t & 1];
            float4 qv;
            qv.x = __expf(__uint_as_float((uint32_t)v0) - sloc);
            qv.y = __expf(__uint_as_float((uint32_t)v1) - sloc);
            qv.z = __expf(__uint_as_float((uint32_t)v2) - sloc);
            qv.w = __expf(__uint_as_float((uint32_t)v3) - sloc);
            ((float4*)qb)[tid] = qv;
            __syncthreads();

            float a0 = 0.f, a1 = 0.f, a2 = 0.f, a3 = 0.f;
            #pragma unroll
            for (int k = 0; k < 16; ++k) {
                const float q = qb[lane + 64 * k];   // conflict-free ds_read_b32
                a0 += q * E[k][0]; a1 += q * E[k][1];
                a2 += q * E[k][2]; a3 += q * E[k][3];
            }

            {   // split-reduction: 4 accs -> 1 per lane (col = cl)
                const bool h1 = lane & 1;
                float s0 = h1 ? a0 : a2;  float r0 = __shfl_xor(s0, 1, 64);
                float s1 = h1 ? a1 : a3;  float r1 = __shfl_xor(s1, 1, 64);
                a0 = (h1 ? a2 : a0) + r0;
                a1 = (h1 ? a3 : a1) + r1;
                const bool h2 = lane & 2;
                float s2 = h2 ? a0 : a1;  float r2 = __shfl_xor(s2, 2, 64);
                a0 = (h2 ? a1 : a0) + r2;
            }
            float s = a0;
            s += __shfl_xor(s, 4, 64);
            s += __shfl_xor(s, 8, 64);
            s += __shfl_xor(s, 16, 64);
            s += __shfl_xor(s, 32, 64);

            const float nv = sloc + __logf(s) + fe;
            if (lane < 4)
                STA(&wbuf[gcb + cl], pack_su(t, nv));
        }

        // ---------- block 0: combine logZ = lse(f_{1023} + b_{1023}) - gold ----------
        if (b == 0) {
            const uint64_t* fp = fb1 + 4 * tid;     // t=1023 odd -> fb1
            const uint64_t* bp = bb0 + 4 * tid;     // s=1024 even -> bb0
            uint64_t f0, f1, f2, f3, g0, g1, g2, g3;
            int n = 0;
            for (;;) {
                f0 = LDA(fp + 0); f1 = LDA(fp + 1); f2 = LDA(fp + 2); f3 = LDA(fp + 3);
                g0 = LDA(bp + 0); g1 = LDA(bp + 1); g2 = LDA(bp + 2); g3 = LDA(bp + 3);
                bool ready = ((int)(f0 >> 32) >= TMID) & ((int)(f1 >> 32) >= TMID) &
                             ((int)(f2 >> 32) >= TMID) & ((int)(f3 >> 32) >= TMID) &
                             ((int)(g0 >> 32) >= BSTEPS) & ((int)(g1 >> 32) >= BSTEPS) &
                             ((int)(g2 >> 32) >= BSTEPS) & ((int)(g3 >> 32) >= BSTEPS);
                if (ready || ++n >= SPIN_MAX) break;
            }
            float sv[4] = {
                __uint_as_float((uint32_t)f0) + __uint_as_float((uint32_t)g0),
                __uint_as_float((uint32_t)f1) + __uint_as_float((uint32_t)g1),
                __uint_as_float((uint32_t)f2) + __uint_as_float((uint32_t)g2),
                __uint_as_float((uint32_t)f3) + __uint_as_float((uint32_t)g3) };
            float mx = fmaxf(fmaxf(sv[0], sv[1]), fmaxf(sv[2], sv[3]));
            #pragma unroll
            for (int m = 32; m; m >>= 1) mx = fmaxf(mx, __shfl_xor(mx, m, 64));
            if (lane == 0) red[wv] = mx;
            __syncthreads();
            const float M = fmaxf(fmaxf(red[0], red[1]), fmaxf(red[2], red[3]));
            float sm = 0.f;
            #pragma unroll
            for (int k = 0; k < 4; ++k) sm += __expf(sv[k] - M);
            #pragma unroll
            for (int m = 32; m; m >>= 1) sm += __shfl_xor(sm, m, 64);
            if (lane == 0) red[4 + wv] = sm;
            __syncthreads();
            if (tid == 0) {
                const float S = red[4] + red[5] + red[6] + red[7];
                const float lse = M + __logf(S);
                uint64_t g = LDA(goldslot);
                int n2 = 0;
                while ((int)(g >> 32) < 1 && ++n2 < SPIN_MAX) g = LDA(goldslot);
                out[0] = lse - __uint_as_float((uint32_t)g);
            }
        }
        return;
    }

    // ================= BACKWARD chain (blocks 64..127, 1024 steps) =================
    {
        const int rb      = b - NFB;                // 0..63
        const int rowbase = rb * CPB + 4 * wv;      // wave's first global row
        const int shslot  = rb * CPB;               // block-LOCAL shift slot

        // E[k][r] = exp(transfer[(rowbase+r)*L + lane+64k]) — coalesced staging
        float E[16][4];
        #pragma unroll
        for (int r = 0; r < 4; ++r) {
            const float* rowp = transfer + (size_t)(rowbase + r) * L + lane;
            #pragma unroll
            for (int k = 0; k < 16; ++k)
                E[k][r] = __expf(rowp[64 * k]);
        }

        if (tid < CPB) {                            // b_{2047} = 0, tag 0
            int j = rb * CPB + tid;
            STA(&bb0[j], pack_su(0, 0.f));
        }

        for (int s = 1; s <= BSTEPS; ++s) {
            uint64_t* rbuf = (s & 1) ? bb0 : bb1;
            uint64_t* wbuf = (s & 1) ? bb1 : bb0;
            const int expect = s - 1;
            const int t = T_LEN - s;                // emission row for this step

            // prefetch emission chunk for my 4 j's (overlaps poll)
            const float4 fv = *(const float4*)(feats + (size_t)t * L + 4 * tid);

            const uint64_t* rp = rbuf + 4 * tid;
            uint64_t v0, v1, v2, v3, vs;
            int n = 0;
            for (;;) {
                v0 = LDA(rp + 0); v1 = LDA(rp + 1);
                v2 = LDA(rp + 2); v3 = LDA(rp + 3);
                vs = LDA(rbuf + shslot);
                bool ready = ((int)(v0 >> 32) >= expect) & ((int)(v1 >> 32) >= expect) &
                             ((int)(v2 >> 32) >= expect) & ((int)(v3 >> 32) >= expect) &
                             ((int)(vs >> 32) >= expect);
                if (ready || ++n >= SPIN_MAX) break;
            }
            const float sb = __uint_as_float((uint32_t)vs);

            // w_j = exp(feats[t][j] + b[j] - sb) -> LDS broadcast
            float* qb = qbuf[s & 1];
            float4 wv4;
            wv4.x = __expf(fv.x + __uint_as_float((uint32_t)v0) - sb);
            wv4.y = __expf(fv.y + __uint_as_float((uint32_t)v1) - sb);
            wv4.z = __expf(fv.z + __uint_as_float((uint32_t)v2) - sb);
            wv4.w = __expf(fv.w + __uint_as_float((uint32_t)v3) - sb);
            ((float4*)qb)[tid] = wv4;
            __syncthreads();

            // matvec: acc[r] += w[lane+64k] * E[k][r]
            float a0 = 0.f, a1 = 0.f, a2 = 0.f, a3 = 0.f;
            #pragma unroll
            for (int k = 0; k < 16; ++k) {
                const float w = qb[lane + 64 * k];
                a0 += w * E[k][0]; a1 += w * E[k][1];
                a2 += w * E[k][2]; a3 += w * E[k][3];
            }

            {   // split-reduction: 4 accs -> 1 per lane (row = cl)
                const bool h1 = lane & 1;
                float s0 = h1 ? a0 : a2;  float r0 = __shfl_xor(s0, 1, 64);
                float s1 = h1 ? a1 : a3;  float r1 = __shfl_xor(s1, 1, 64);
                a0 = (h1 ? a2 : a0) + r0;
                a1 = (h1 ? a3 : a1) + r1;
                const bool h2 = lane & 2;
                float s2 = h2 ? a0 : a1;  float r2 = __shfl_xor(s2, 2, 64);
                a0 = (h2 ? a1 : a0) + r2;
            }
            float sum = a0;
            sum += __shfl_xor(sum, 4, 64);
            sum += __shfl_xor(sum, 8, 64);
            sum += __shfl_xor(sum, 16, 64);
            sum += __shfl_xor(sum, 32, 64);

            const float nb = sb + __logf(sum);      // emission already inside w
            if (lane < 4)
                STA(&wbuf[rowbase + cl], pack_su(s, nb));
        }
    }
}

// =====================================================================
// Fallback: the proven R4 single-forward-chain kernel (4.16 ms).
// Requires only (2*L + 1) * 8 = 16392 bytes of ws.
// =====================================================================
__global__ __launch_bounds__(TPB, 1)
void crf_single(const float* __restrict__ feats,
                const float* __restrict__ transfer,
                const int* __restrict__ target,
                float* __restrict__ out,
                uint64_t* __restrict__ ws64)
{
    __shared__ __align__(16) float qbuf[2][L];
    __shared__ float red[8];

    uint64_t* buf0 = ws64;
    uint64_t* buf1 = ws64 + L;
    uint64_t* goldslot = ws64 + 2 * L;

    const int b   = blockIdx.x;
    const int tid = threadIdx.x;
    const int lane = tid & 63;
    const int wv   = tid >> 6;
    const int cl   = 2 * (lane & 1) + ((lane >> 1) & 1);

    if (b == NFB) {   // gold block
        float s = 0.f;
        for (int t = tid; t < T_LEN; t += TPB)
            s += feats[t * L + target[t]];
        for (int t = tid; t < T_LEN - 1; t += TPB)
            s += transfer[target[t] * L + target[t + 1]];
        #pragma unroll
        for (int m = 32; m; m >>= 1) s += __shfl_xor(s, m, 64);
        if (lane == 0) red[wv] = s;
        __syncthreads();
        if (tid == 0) {
            float g = red[0] + red[1] + red[2] + red[3];
            STA(goldslot, pack_su(1, g));
        }
        return;
    }

    const int gcb    = b * CPB + 4 * wv;
    const int shslot = b * CPB;

    float E[16][4];
    #pragma unroll
    for (int k = 0; k < 16; ++k) {
        const float4 r = *(const float4*)(transfer + (size_t)(lane + 64 * k) * L + gcb);
        E[k][0] = __expf(r.x); E[k][1] = __expf(r.y);
        E[k][2] = __expf(r.z); E[k][3] = __expf(r.w);
    }

    if (tid < CPB) {
        int j = b * CPB + tid;
        STA(&buf0[j], pack_su(0, feats[j]));
    }

    for (int t = 1; t < T_LEN; ++t) {
        uint64_t* rbuf = (t & 1) ? buf0 : buf1;
        uint64_t* wbuf = (t & 1) ? buf1 : buf0;
        const int expect = t - 1;
        const float fe = feats[(size_t)t * L + gcb + cl];

        const uint64_t* rp = rbuf + 4 * tid;
        uint64_t v0, v1, v2, v3, vs;
        int n = 0;
        for (;;) {
            v0 = LDA(rp + 0); v1 = LDA(rp + 1);
            v2 = LDA(rp + 2); v3 = LDA(rp + 3);
            vs = LDA(rbuf + shslot);
            bool ready = ((int)(v0 >> 32) >= expect) & ((int)(v1 >> 32) >= expect) &
                         ((int)(v2 >> 32) >= expect) & ((int)(v3 >> 32) >= expect) &
                         ((int)(vs >> 32) >= expect);
            if (ready || ++n >= SPIN_MAX) break;
        }
        const float sloc = __uint_as_float((uint32_t)vs);

        float* qb = qbuf[t & 1];
        float4 qv;
        qv.x = __expf(__uint_as_float((uint32_t)v0) - sloc);
        qv.y = __expf(__uint_as_float((uint32_t)v1) - sloc);
        qv.z = __expf(__uint_as_float((uint32_t)v2) - sloc);
        qv.w = __expf(__uint_as_float((uint32_t)v3) - sloc);
        ((float4*)qb)[tid] = qv;
        __syncthreads();

        float a0 = 0.f, a1 = 0.f, a2 = 0.f, a3 = 0.f;
        #pragma unroll
        for (int k = 0; k < 16; ++k) {
            const float q = qb[lane + 64 * k];
            a0 += q * E[k][0]; a1 += q * E[k][1];
            a2 += q * E[k][2]; a3 += q * E[k][3];
        }
        {
            const bool h1 = lane & 1;
            float s0 = h1 ? a0 : a2;  float r0 = __shfl_xor(s0, 1, 64);
            float s1 = h1 ? a1 : a3;  float r1 = __shfl_xor(s1, 1, 64);
            a0 = (h1 ? a2 : a0) + r0;
            a1 = (h1 ? a3 : a1) + r1;
            const bool h2 = lane & 2;
            float s2 = h2 ? a0 : a1;  float r2 = __shfl_xor(s2, 2, 64);
            a0 = (h2 ? a1 : a0) + r2;
        }
        float s = a0;
        s += __shfl_xor(s, 4, 64);
        s += __shfl_xor(s, 8, 64);
        s += __shfl_xor(s, 16, 64);
        s += __shfl_xor(s, 32, 64);

        const float nv = sloc + __logf(s) + fe;
        if (lane < 4)
            STA(&wbuf[gcb + cl], pack_su(t, nv));
    }

    if (b == 0) {
        const uint64_t* fp = buf1 + 4 * tid;
        uint64_t v0, v1, v2, v3;
        int n = 0;
        for (;;) {
            v0 = LDA(fp + 0); v1 = LDA(fp + 1);
            v2 = LDA(fp + 2); v3 = LDA(fp + 3);
            bool ready = ((int)(v0 >> 32) >= T_LEN - 1) & ((int)(v1 >> 32) >= T_LEN - 1) &
                         ((int)(v2 >> 32) >= T_LEN - 1) & ((int)(v3 >> 32) >= T_LEN - 1);
            if (ready || ++n >= SPIN_MAX) break;
        }
        float sv[4] = { __uint_as_float((uint32_t)v0), __uint_as_float((uint32_t)v1),
                        __uint_as_float((uint32_t)v2), __uint_as_float((uint32_t)v3) };
        float mx = fmaxf(fmaxf(sv[0], sv[1]), fmaxf(sv[2], sv[3]));
        #pragma unroll
        for (int m = 32; m; m >>= 1) mx = fmaxf(mx, __shfl_xor(mx, m, 64));
        if (lane == 0) red[wv] = mx;
        __syncthreads();
        const float M = fmaxf(fmaxf(red[0], red[1]), fmaxf(red[2], red[3]));
        float sm = 0.f;
        #pragma unroll
        for (int k = 0; k < 4; ++k) sm += __expf(sv[k] - M);
        #pragma unroll
        for (int m = 32; m; m >>= 1) sm += __shfl_xor(sm, m, 64);
        if (lane == 0) red[4 + wv] = sm;
        __syncthreads();
        if (tid == 0) {
            const float S = red[4] + red[5] + red[6] + red[7];
            const float lse = M + __logf(S);
            uint64_t g = LDA(goldslot);
            int n2 = 0;
            while ((int)(g >> 32) < 1 && ++n2 < SPIN_MAX) g = LDA(goldslot);
            out[0] = lse - __uint_as_float((uint32_t)g);
        }
    }
}

extern "C" void kernel_launch(void* const* d_in, const int* in_sizes, int n_in,
                              void* d_out, int out_size, void* d_ws, size_t ws_size,
                              hipStream_t stream) {
    const float* feats    = (const float*)d_in[0];
    const float* transfer = (const float*)d_in[1];
    const int*   target   = (const int*)d_in[2];
    float* out = (float*)d_out;
    uint64_t* ws64 = (uint64_t*)d_ws;

    if (ws_size >= (4 * L + 1) * sizeof(uint64_t)) {
        // meet-in-the-middle: forward + backward chains, critical path 1024 steps
        hipLaunchKernelGGL(crf_mitm, dim3(GOLDB + 1), dim3(TPB), 0, stream,
                           feats, transfer, target, out, ws64);
    } else {
        // proven single-chain fallback (R4): needs only 16392 B of ws
        hipLaunchKernelGGL(crf_single, dim3(NFB + 1), dim3(TPB), 0, stream,
                           feats, transfer, target, out, ws64);
    }
}